// Round 2
// baseline (13879.999 us; speedup 1.0000x reference)
//
#include <hip/hip_runtime.h>
#include <hip/hip_bf16.h>

// Elman RNN: B=128, T=256, I=512, H=1024
//   Phase 1: xp[t,b,h] = x[b,t,:] . W_ih[h,:] + b_ih   (big MFMA GEMM, bf16)
//   Phase 2: persistent kernel, all 256 steps, W_hh in registers,
//            device-scope atomic grid barrier between steps.
// Precision: bf16 inputs, fp32 MFMA accumulate, fp32 tanh, fp32 output.

#define B_SZ 128
#define T_SZ 256
#define I_SZ 512
#define H_SZ 1024
#define GRID_P 256   // persistent grid: 8 m-tiles x 32 n-tiles

typedef __bf16 bf16x8 __attribute__((ext_vector_type(8)));
typedef __bf16 bf16x4 __attribute__((ext_vector_type(4)));
typedef float f32x4 __attribute__((ext_vector_type(4)));

// ---------------- fp32 -> bf16 convert (vectorized x4) ----------------
__global__ void cvt_kernel(const float* __restrict__ src, __bf16* __restrict__ dst, int n4) {
    int i = blockIdx.x * blockDim.x + threadIdx.x;
    if (i < n4) {
        float4 v = reinterpret_cast<const float4*>(src)[i];
        bf16x4 o;
        o[0] = (__bf16)v.x; o[1] = (__bf16)v.y; o[2] = (__bf16)v.z; o[3] = (__bf16)v.w;
        reinterpret_cast<bf16x4*>(dst)[i] = o;
    }
}

// ---------------- input projection -> xp stored [T,B,H] ----------------
// grid: (BT/16, H/64), block 256 (4 waves, each wave one 16x16 n-subtile)
__global__ __launch_bounds__(256) void proj_kernel(const __bf16* __restrict__ x,
                                                   const __bf16* __restrict__ wih,
                                                   const float* __restrict__ bih,
                                                   __bf16* __restrict__ xp) {
    const int m0   = blockIdx.x * 16;      // bt row tile
    const int n0   = blockIdx.y * 64;
    const int lane = threadIdx.x & 63;
    const int wave = threadIdx.x >> 6;
    const int lm   = lane & 15;
    const int quad = lane >> 4;
    const int nw   = n0 + wave * 16;

    f32x4 acc = {0.f, 0.f, 0.f, 0.f};
    const __bf16* arow = x   + (size_t)(m0 + lm) * I_SZ + quad * 8;
    const __bf16* brow = wih + (size_t)(nw + lm) * I_SZ + quad * 8;
#pragma unroll 4
    for (int k = 0; k < I_SZ; k += 32) {
        bf16x8 a = *reinterpret_cast<const bf16x8*>(arow + k);
        bf16x8 b = *reinterpret_cast<const bf16x8*>(brow + k);
        acc = __builtin_amdgcn_mfma_f32_16x16x32_bf16(a, b, acc, 0, 0, 0);
    }
    const int col  = nw + lm;
    const float bias = bih[col];
#pragma unroll
    for (int r = 0; r < 4; ++r) {
        int row = m0 + quad * 4 + r;       // bt index: b = row>>8, t = row&255
        int b   = row >> 8;
        int t   = row & (T_SZ - 1);
        xp[((size_t)t * B_SZ + b) * H_SZ + col] = (__bf16)(acc[r] + bias);
    }
}

// ---------------- persistent recurrence ----------------
// 256 blocks x 256 threads. block = (mt = bid&7 -> 16 batch rows) x (nt = bid>>3 -> 32 cols)
// waves: ns = wave&1 (n-subtile of 16), kh = wave>>1 (k half of 512)
// Each wave pins W_hh[n-sub rows, k-half] in 64 VGPRs for all 256 steps.
__global__ __launch_bounds__(256, 2) void rnn_persist(const __bf16* __restrict__ whh,
                                                      const __bf16* __restrict__ xp,
                                                      const float* __restrict__ bhh,
                                                      __bf16* __restrict__ hA,
                                                      __bf16* __restrict__ hB,
                                                      float* __restrict__ states,
                                                      float* __restrict__ hlast,
                                                      unsigned* __restrict__ cnt) {
    __shared__ float red[2][64][4];        // k-half partial sums, per n-sub

    const int tid  = threadIdx.x;
    const int lane = tid & 63;
    const int wave = tid >> 6;
    const int ns   = wave & 1;
    const int kh   = wave >> 1;
    const int bid  = blockIdx.x;
    const int m0   = (bid & 7) * 16;
    const int n0   = (bid >> 3) * 32;
    const int lm   = lane & 15;
    const int quad = lane >> 4;
    const int nrow = n0 + ns * 16 + lm;    // W_hh row == output column
    const int koff = kh * 512;

    // ---- pin W_hh slice in registers (one-time) ----
    bf16x8 w[16];
    {
        const __bf16* wb = whh + (size_t)nrow * H_SZ + koff + quad * 8;
#pragma unroll
        for (int i = 0; i < 16; ++i) w[i] = *reinterpret_cast<const bf16x8*>(wb + i * 32);
    }
    const float bias = bhh[nrow];

    // per-r constant address parts (epilogue, kh==0 waves)
    size_t st_base[4], xp_base[4], h_base[4];
#pragma unroll
    for (int r = 0; r < 4; ++r) {
        int row = m0 + quad * 4 + r;                       // batch index
        st_base[r] = (size_t)row * T_SZ * H_SZ + nrow;     // + t*H
        xp_base[r] = (size_t)row * H_SZ + nrow;            // + t*B*H
        h_base[r]  = (size_t)row * H_SZ + nrow;
    }

    for (int t = 0; t < T_SZ; ++t) {
        const __bf16* cur = (t & 1) ? hB : hA;
        __bf16*       nxt = (t & 1) ? hA : hB;

        // ---- load A-frags (h slice) ----
        bf16x8 a[16];
        const __bf16* ab = cur + (size_t)(m0 + lm) * H_SZ + koff + quad * 8;
#pragma unroll
        for (int i = 0; i < 16; ++i) a[i] = *reinterpret_cast<const bf16x8*>(ab + i * 32);

        f32x4 acc = {0.f, 0.f, 0.f, 0.f};
#pragma unroll
        for (int i = 0; i < 16; ++i)
            acc = __builtin_amdgcn_mfma_f32_16x16x32_bf16(a[i], w[i], acc, 0, 0, 0);

        // ---- k-half reduce through LDS ----
        if (kh == 1) {
            red[ns][lane][0] = acc[0]; red[ns][lane][1] = acc[1];
            red[ns][lane][2] = acc[2]; red[ns][lane][3] = acc[3];
        }
        __syncthreads();
        if (kh == 0) {
#pragma unroll
            for (int r = 0; r < 4; ++r) {
                float u = acc[r] + red[ns][lane][r]
                        + (float)xp[(size_t)t * B_SZ * H_SZ + xp_base[r]] + bias;
                float h = tanhf(u);
                states[st_base[r] + (size_t)t * H_SZ] = h;
                nxt[h_base[r]] = (__bf16)h;
                if (t == T_SZ - 1) hlast[h_base[r]] = h;
            }
        }

        // ---- device-scope grid barrier ----
        __threadfence();          // flush this thread's h/state writes to device scope
        __syncthreads();          // all threads' stores issued & fenced
        if (tid == 0) {
            __hip_atomic_fetch_add(cnt, 1u, __ATOMIC_RELEASE, __HIP_MEMORY_SCOPE_AGENT);
            const unsigned target = (unsigned)GRID_P * (unsigned)(t + 1);
            while (__hip_atomic_load(cnt, __ATOMIC_ACQUIRE, __HIP_MEMORY_SCOPE_AGENT) < target)
                __builtin_amdgcn_s_sleep(1);
        }
        __syncthreads();
        __threadfence();          // invalidate stale h in L1 before next step's reads
    }
}

extern "C" void kernel_launch(void* const* d_in, const int* in_sizes, int n_in,
                              void* d_out, int out_size, void* d_ws, size_t ws_size,
                              hipStream_t stream) {
    const float* x    = (const float*)d_in[0];   // [B,T,I]
    const float* Wih  = (const float*)d_in[1];   // [H,I]
    const float* Whh  = (const float*)d_in[2];   // [H,H]
    const float* bih  = (const float*)d_in[3];   // [H]
    const float* bhh  = (const float*)d_in[4];   // [H]

    float* states = (float*)d_out;                               // [B,T,H]
    float* hlast  = (float*)d_out + (size_t)B_SZ * T_SZ * H_SZ;  // [B,H]

    // workspace carve (bytes), all 16B aligned
    char* w = (char*)d_ws;
    __bf16* x_bf   = (__bf16*)w;  w += (size_t)B_SZ * T_SZ * I_SZ * 2;  // 33.5 MB
    __bf16* wih_bf = (__bf16*)w;  w += (size_t)H_SZ * I_SZ * 2;         // 1 MB
    __bf16* whh_bf = (__bf16*)w;  w += (size_t)H_SZ * H_SZ * 2;         // 2 MB
    __bf16* xp_bf  = (__bf16*)w;  w += (size_t)B_SZ * T_SZ * H_SZ * 2;  // 67 MB, [T,B,H]
    __bf16* hA     = (__bf16*)w;  w += (size_t)B_SZ * H_SZ * 2;         // 256 KB
    __bf16* hB     = (__bf16*)w;  w += (size_t)B_SZ * H_SZ * 2;         // 256 KB
    unsigned* cnt  = (unsigned*)w; w += 256;                            // barrier counter
    (void)ws_size;

    // converts
    {
        int n4 = B_SZ * T_SZ * I_SZ / 4;
        cvt_kernel<<<(n4 + 255) / 256, 256, 0, stream>>>(x, x_bf, n4);
    }
    {
        int n4 = H_SZ * I_SZ / 4;
        cvt_kernel<<<(n4 + 255) / 256, 256, 0, stream>>>(Wih, wih_bf, n4);
    }
    {
        int n4 = H_SZ * H_SZ / 4;
        cvt_kernel<<<(n4 + 255) / 256, 256, 0, stream>>>(Whh, whh_bf, n4);
    }

    // h0 = 0, barrier counter = 0 (ws is re-poisoned 0xAA before every launch)
    hipMemsetAsync(hA, 0, (size_t)B_SZ * H_SZ * 2, stream);
    hipMemsetAsync(cnt, 0, 256, stream);

    // input projection
    {
        dim3 grid(B_SZ * T_SZ / 16, H_SZ / 64);  // (2048, 16)
        proj_kernel<<<grid, 256, 0, stream>>>(x_bf, wih_bf, bih, xp_bf);
    }

    // persistent recurrence: one kernel, 256 internal steps
    rnn_persist<<<GRID_P, 256, 0, stream>>>(whh_bf, xp_bf, bhh, hA, hB,
                                            states, hlast, cnt);
}

// Round 3
// 2968.853 us; speedup vs baseline: 4.6752x; 4.6752x over previous
//
#include <hip/hip_runtime.h>
#include <hip/hip_bf16.h>

// Elman RNN: B=128, T=256, I=512, H=1024
//   Phase 1: xp[b,h] per t  (big MFMA GEMM, bf16)
//   Phase 2: ONE persistent kernel for all 256 steps.
//     - W_hh slice per block staged once into LDS (frag-ordered, ds_read_b128)
//     - h exchanged cross-block via AGENT-scope relaxed atomics (MALL-coherent,
//       bypasses non-coherent L1/per-XCD L2) -> NO threadfence / wbl2 / inv.
//     - grid barrier: relaxed fetch_add + relaxed spin; ordering via
//       __syncthreads()'s vmcnt(0) drain before the arrive.
// Precision: bf16 inputs, fp32 MFMA accumulate, fp32 tanh, fp32 output.

#define B_SZ 128
#define T_SZ 256
#define I_SZ 512
#define H_SZ 1024
#define GRID_P 256   // 8 m-tiles (16 batch) x 32 n-tiles (32 cols)

typedef __bf16 bf16x8 __attribute__((ext_vector_type(8)));
typedef __bf16 bf16x4 __attribute__((ext_vector_type(4)));
typedef float f32x4 __attribute__((ext_vector_type(4)));
typedef unsigned long long u64;

__device__ __forceinline__ float fast_tanh(float x) {
    // exact at +-inf saturation, ~1e-6 abs err; bf16 noise dominates anyway
    return 1.0f - 2.0f / (__expf(2.0f * x) + 1.0f);
}

// ---------------- fp32 -> bf16 convert (vectorized x4) ----------------
__global__ void cvt_kernel(const float* __restrict__ src, __bf16* __restrict__ dst, int n4) {
    int i = blockIdx.x * blockDim.x + threadIdx.x;
    if (i < n4) {
        float4 v = reinterpret_cast<const float4*>(src)[i];
        bf16x4 o;
        o[0] = (__bf16)v.x; o[1] = (__bf16)v.y; o[2] = (__bf16)v.z; o[3] = (__bf16)v.w;
        reinterpret_cast<bf16x4*>(dst)[i] = o;
    }
}

// ---------------- input projection -> xp stored [T,B,H] ----------------
__global__ __launch_bounds__(256) void proj_kernel(const __bf16* __restrict__ x,
                                                   const __bf16* __restrict__ wih,
                                                   const float* __restrict__ bih,
                                                   __bf16* __restrict__ xp) {
    const int m0   = blockIdx.x * 16;      // bt row tile
    const int n0   = blockIdx.y * 64;
    const int lane = threadIdx.x & 63;
    const int wave = threadIdx.x >> 6;
    const int lm   = lane & 15;
    const int quad = lane >> 4;
    const int nw   = n0 + wave * 16;

    f32x4 acc = {0.f, 0.f, 0.f, 0.f};
    const __bf16* arow = x   + (size_t)(m0 + lm) * I_SZ + quad * 8;
    const __bf16* brow = wih + (size_t)(nw + lm) * I_SZ + quad * 8;
#pragma unroll 4
    for (int k = 0; k < I_SZ; k += 32) {
        bf16x8 a = *reinterpret_cast<const bf16x8*>(arow + k);
        bf16x8 b = *reinterpret_cast<const bf16x8*>(brow + k);
        acc = __builtin_amdgcn_mfma_f32_16x16x32_bf16(a, b, acc, 0, 0, 0);
    }
    const int col  = nw + lm;
    const float bias = bih[col];
#pragma unroll
    for (int r = 0; r < 4; ++r) {
        int row = m0 + quad * 4 + r;       // bt index: b = row>>8, t = row&255
        int b   = row >> 8;
        int t   = row & (T_SZ - 1);
        xp[((size_t)t * B_SZ + b) * H_SZ + col] = (__bf16)(acc[r] + bias);
    }
}

// ---------------- persistent recurrence ----------------
// 256 blocks x 256 threads. block = 16 batch rows x 32 cols.
// waves: ns = wave&1 (16-col subtile), kh = wave>>1 (K half of 512).
__global__ __launch_bounds__(256, 2) void rnn_persist(const __bf16* __restrict__ whh,
                                                      const __bf16* __restrict__ xp,
                                                      const float* __restrict__ bhh,
                                                      __bf16* __restrict__ hA,
                                                      __bf16* __restrict__ hB,
                                                      float* __restrict__ states,
                                                      float* __restrict__ hlast,
                                                      unsigned* __restrict__ cnt) {
    __shared__ __bf16 wlds[32 * 1024];     // 64 KB, frag-ordered W slice
    __shared__ float  red[2][64][4];       // k-half partial sums
    __shared__ __bf16 htile[16 * 32];      // h transpose tile (rows x cols)

    const int tid  = threadIdx.x;
    const int lane = tid & 63;
    const int wave = tid >> 6;
    const int ns   = wave & 1;
    const int kh   = wave >> 1;
    const int bid  = blockIdx.x;
    const int m0   = (bid & 7) * 16;
    const int n0   = (bid >> 3) * 32;
    const int lm   = lane & 15;
    const int quad = lane >> 4;
    const int nrow = n0 + ns * 16 + lm;    // W_hh row == output column
    const int koff = kh * 512;

    // ---- stage W slice into LDS, frag-ordered (each thread copies its own frags) ----
    bf16x8* wf = (bf16x8*)wlds;
    {
        const bf16x8* src = (const bf16x8*)(whh + (size_t)nrow * H_SZ + koff + quad * 8);
#pragma unroll
        for (int i = 0; i < 16; ++i)
            wf[((kh * 16 + i) * 2 + ns) * 64 + lane] = src[i * 4];   // i*4 x bf16x8 = i*32 elems
    }
    const float bias = bhh[nrow];

    size_t st_base[4], xp_base[4], hl_base[4];
#pragma unroll
    for (int r = 0; r < 4; ++r) {
        int row = m0 + quad * 4 + r;                       // batch index
        st_base[r] = (size_t)row * T_SZ * H_SZ + nrow;     // + t*H
        xp_base[r] = (size_t)row * H_SZ + nrow;            // + t*B*H
        hl_base[r] = (size_t)row * H_SZ + nrow;
    }
    __syncthreads();

    for (int t = 0; t < T_SZ; ++t) {
        const __bf16* cur = (t & 1) ? hB : hA;
        __bf16*       nxt = (t & 1) ? hA : hB;

        // ---- load h A-frags via AGENT-scope relaxed 8B atomic loads (MALL-coherent) ----
        const u64* ap = (const u64*)(cur + (size_t)(m0 + lm) * H_SZ + koff + quad * 8);
        u64 a0[16], a1[16];
#pragma unroll
        for (int i = 0; i < 16; ++i) {
            a0[i] = __hip_atomic_load(ap + i * 8,     __ATOMIC_RELAXED, __HIP_MEMORY_SCOPE_AGENT);
            a1[i] = __hip_atomic_load(ap + i * 8 + 1, __ATOMIC_RELAXED, __HIP_MEMORY_SCOPE_AGENT);
        }

        f32x4 acc = {0.f, 0.f, 0.f, 0.f};
#pragma unroll
        for (int i = 0; i < 16; ++i) {
            union { u64 u[2]; bf16x8 v; } au;
            au.u[0] = a0[i]; au.u[1] = a1[i];
            acc = __builtin_amdgcn_mfma_f32_16x16x32_bf16(
                au.v, wf[((kh * 16 + i) * 2 + ns) * 64 + lane], acc, 0, 0, 0);
        }

        // ---- k-half reduce through LDS ----
        if (kh == 1) {
            red[ns][lane][0] = acc[0]; red[ns][lane][1] = acc[1];
            red[ns][lane][2] = acc[2]; red[ns][lane][3] = acc[3];
        }
        __syncthreads();
        if (kh == 0) {
#pragma unroll
            for (int r = 0; r < 4; ++r) {
                float u = acc[r] + red[ns][lane][r]
                        + (float)xp[(size_t)t * B_SZ * H_SZ + xp_base[r]] + bias;
                float h = fast_tanh(u);
                states[st_base[r] + (size_t)t * H_SZ] = h;       // normal store (flushed at kernel end)
                if (t == T_SZ - 1) hlast[hl_base[r]] = h;
                htile[(quad * 4 + r) * 32 + (ns * 16 + lm)] = (__bf16)h;
            }
        }
        __syncthreads();

        // ---- wave 0 stores packed h to global via AGENT-scope atomics ----
        if (wave == 0) {
            const unsigned* ht32 = (const unsigned*)htile;
            unsigned* nxt32 = (unsigned*)nxt;
#pragma unroll
            for (int rr = 0; rr < 4; ++rr) {
                int w2  = lane + 64 * rr;          // 0..255 packed-uint index
                int row = w2 >> 4;                 // 0..15
                int c2  = w2 & 15;                 // 0..15 (pairs of cols)
                __hip_atomic_store(nxt32 + (size_t)(m0 + row) * (H_SZ / 2) + (n0 >> 1) + c2,
                                   ht32[w2], __ATOMIC_RELAXED, __HIP_MEMORY_SCOPE_AGENT);
            }
        }

        // ---- grid barrier: syncthreads drains vmcnt(0) before the arrive ----
        __syncthreads();
        if (tid == 0) {
            __hip_atomic_fetch_add(cnt, 1u, __ATOMIC_RELAXED, __HIP_MEMORY_SCOPE_AGENT);
            const unsigned target = (unsigned)GRID_P * (unsigned)(t + 1);
            while (__hip_atomic_load(cnt, __ATOMIC_RELAXED, __HIP_MEMORY_SCOPE_AGENT) < target)
                __builtin_amdgcn_s_sleep(2);
        }
        __syncthreads();
    }
}

extern "C" void kernel_launch(void* const* d_in, const int* in_sizes, int n_in,
                              void* d_out, int out_size, void* d_ws, size_t ws_size,
                              hipStream_t stream) {
    const float* x    = (const float*)d_in[0];   // [B,T,I]
    const float* Wih  = (const float*)d_in[1];   // [H,I]
    const float* Whh  = (const float*)d_in[2];   // [H,H]
    const float* bih  = (const float*)d_in[3];   // [H]
    const float* bhh  = (const float*)d_in[4];   // [H]

    float* states = (float*)d_out;                               // [B,T,H]
    float* hlast  = (float*)d_out + (size_t)B_SZ * T_SZ * H_SZ;  // [B,H]

    // workspace carve (bytes), all 16B aligned
    char* w = (char*)d_ws;
    __bf16* x_bf   = (__bf16*)w;  w += (size_t)B_SZ * T_SZ * I_SZ * 2;  // 33.5 MB
    __bf16* wih_bf = (__bf16*)w;  w += (size_t)H_SZ * I_SZ * 2;         // 1 MB
    __bf16* whh_bf = (__bf16*)w;  w += (size_t)H_SZ * H_SZ * 2;         // 2 MB
    __bf16* xp_bf  = (__bf16*)w;  w += (size_t)B_SZ * T_SZ * H_SZ * 2;  // 67 MB, [T,B,H]
    __bf16* hA     = (__bf16*)w;  w += (size_t)B_SZ * H_SZ * 2;         // 256 KB
    __bf16* hB     = (__bf16*)w;  w += (size_t)B_SZ * H_SZ * 2;         // 256 KB
    unsigned* cnt  = (unsigned*)w; w += 256;                            // barrier counter
    (void)ws_size;

    // converts
    {
        int n4 = B_SZ * T_SZ * I_SZ / 4;
        cvt_kernel<<<(n4 + 255) / 256, 256, 0, stream>>>(x, x_bf, n4);
    }
    {
        int n4 = H_SZ * I_SZ / 4;
        cvt_kernel<<<(n4 + 255) / 256, 256, 0, stream>>>(Wih, wih_bf, n4);
    }
    {
        int n4 = H_SZ * H_SZ / 4;
        cvt_kernel<<<(n4 + 255) / 256, 256, 0, stream>>>(Whh, whh_bf, n4);
    }

    // h0 = 0, barrier counter = 0 (ws is re-poisoned 0xAA before every launch)
    hipMemsetAsync(hA, 0, (size_t)B_SZ * H_SZ * 2, stream);
    hipMemsetAsync(cnt, 0, 256, stream);

    // input projection
    {
        dim3 grid(B_SZ * T_SZ / 16, H_SZ / 64);  // (2048, 16)
        proj_kernel<<<grid, 256, 0, stream>>>(x_bf, wih_bf, bih, xp_bf);
    }

    // persistent recurrence: one kernel, 256 internal steps
    rnn_persist<<<GRID_P, 256, 0, stream>>>(whh_bf, xp_bf, bhh, hA, hB,
                                            states, hlast, cnt);
}